// Round 15
// baseline (823.320 us; speedup 1.0000x reference)
//
#include <hip/hip_runtime.h>

// Sparse submanifold 3D conv, Round 15: pair compaction, CORRECTNESS-FIRST.
// R13/R14 failed identically (absmax ~23) -> bug in the new machinery, not
// the readlane. This round removes both remaining suspects:
//  - build_pairs v2: FIXED 64-slot segment per non-center k (no prefix-sum,
//    no segoff); center k=13 is always-valid by construction -> synthetic
//    descriptors (idx = wrow0+slot), no pair memory.
//  - scatter hardened: wlds declared BEFORE accs, srw clamped to dump row
//    192 -> garbage rows can never corrupt W fragments (the suspected ~23
//    amplifier: accs OOB writes previously landed in wlds).
//  - main kernel: NO asm, NO manual vmcnt. Exec-masked plain loads
//    (R7-verified pattern), compiler-scheduled. Optimize after it passes.
// Fallbacks: R12 bf16 dense kernel (83us, verified), then R9 f32.

typedef short          bf16x8 __attribute__((ext_vector_type(8)));
typedef unsigned short u16x8  __attribute__((ext_vector_type(8)));
typedef float          f32x16 __attribute__((ext_vector_type(16)));
typedef float          f32x4a __attribute__((ext_vector_type(4)));
typedef int            i32x4  __attribute__((ext_vector_type(4)));
typedef int            i32x4u __attribute__((ext_vector_type(4), aligned(4)));
typedef int            i32x2u __attribute__((ext_vector_type(2), aligned(4)));

constexpr int CIN   = 32;
constexpr int COUT  = 64;
constexpr int KV    = 27;
constexpr int NFRAG = KV * 4;          // B fragments
constexpr int SLOTS = NFRAG * 64;      // 6912 b128 slots of W
constexpr int WIN   = 192;             // rows per window
constexpr int SEGC  = 64;              // pair slots per non-center k
constexpr int PPW   = 26 * SEGC;       // 1664 ints pair storage per window
constexpr int DSTR  = 64;              // descriptor ints per window
// fallback (R12) geometry
constexpr int WAVES = 16;
constexpr int RPW   = 32;
constexpr int RPB   = WAVES * RPW;     // 512

// ---- asm helpers (fallback kernels only) ----
#define LOADD(g0, g1, voff, rs)                                           \
    asm volatile("buffer_load_dwordx4 %0, %2, %3, 0 offen offset:0\n\t"   \
                 "buffer_load_dwordx4 %1, %2, %3, 0 offen offset:32"      \
                 : "=&v"(g0), "=&v"(g1)                                   \
                 : "v"(voff), "s"(rs))
#define WAIT6(a, b) asm volatile("s_waitcnt vmcnt(6)" : "+v"(a), "+v"(b))
#define WAIT4(a, b) asm volatile("s_waitcnt vmcnt(4)" : "+v"(a), "+v"(b))
#define WAIT2(a, b) asm volatile("s_waitcnt vmcnt(2)" : "+v"(a), "+v"(b))
#define WAIT0(a, b) asm volatile("s_waitcnt vmcnt(0)" : "+v"(a), "+v"(b))
#define LOADQ(g0, g1, g2, g3, voff, rs)                                   \
    asm volatile("buffer_load_dwordx4 %0, %4, %5, 0 offen offset:0\n\t"   \
                 "buffer_load_dwordx4 %1, %4, %5, 0 offen offset:16\n\t"  \
                 "buffer_load_dwordx4 %2, %4, %5, 0 offen offset:64\n\t"  \
                 "buffer_load_dwordx4 %3, %4, %5, 0 offen offset:80"      \
                 : "=&v"(g0), "=&v"(g1), "=&v"(g2), "=&v"(g3)             \
                 : "v"(voff), "s"(rs))
#define WAITV4(a, b, c, d) \
    asm volatile("s_waitcnt vmcnt(4)" : "+v"(a), "+v"(b), "+v"(c), "+v"(d))
#define WAITV0(a, b, c, d) \
    asm volatile("s_waitcnt vmcnt(0)" : "+v"(a), "+v"(b), "+v"(c), "+v"(d))

__device__ inline bf16x8 cvt8(f32x4a lo, f32x4a hi) {
    bf16x8 r;
#pragma unroll
    for (int j = 0; j < 4; ++j) {
        r[j]     = __builtin_bit_cast(short, (__bf16)lo[j]);
        r[4 + j] = __builtin_bit_cast(short, (__bf16)hi[j]);
    }
    return r;
}

#define NIDX(A, B, C, k) ((k) < 24 ? (A)[(k) >> 2][(k) & 3] \
                                   : ((k) < 26 ? (B)[(k) - 24] : (C)))

// =================== prepass kernels ===================

__global__ __launch_bounds__(256)
void feats_to_bf16(const float* __restrict__ in,
                   unsigned short* __restrict__ outp, int ngroups)
{
    int i = blockIdx.x * 256 + threadIdx.x;
    const int stride = gridDim.x * 256;
    for (; i < ngroups; i += stride) {
        const f32x4a a = *(const f32x4a*)(in + (size_t)i * 8);
        const f32x4a b = *(const f32x4a*)(in + (size_t)i * 8 + 4);
        u16x8 t;
#pragma unroll
        for (int j = 0; j < 4; ++j) {
            t[j]     = __builtin_bit_cast(unsigned short, (__bf16)a[j]);
            t[4 + j] = __builtin_bit_cast(unsigned short, (__bf16)b[j]);
        }
        *(u16x8*)(outp + (size_t)i * 8) = t;
    }
}

__global__ __launch_bounds__(256)
void build_wfrag(const float* __restrict__ weight,
                 unsigned short* __restrict__ wf)
{
    const int s = blockIdx.x * 256 + threadIdx.x;   // b128 slot
    if (s < SLOTS) {
        const int frag = s >> 6, ln = s & 63;
        const int k  = frag >> 2;
        const int cc = (frag >> 1) & 1;
        const int h  = frag & 1;
        const int co  = (ln & 31) + (h << 5);
        const int cib = (cc << 4) + ((ln >> 5) << 3);
        const float* src = weight + k * 2048 + cib * 64 + co;
        u16x8 t;
#pragma unroll
        for (int j = 0; j < 8; ++j)
            t[j] = __builtin_bit_cast(unsigned short, (__bf16)src[j * 64]);
        *(u16x8*)(wf + (size_t)s * 8) = t;
    }
}

// v2: fixed 64-slot segment per non-center k (s = 0..25 maps to k, skipping
// 13). pair = idx | row<<19. Descriptor = off<<11 | len<<5 | k; center k=13
// descriptors are synthetic (off = row offset within window).
__global__ __launch_bounds__(256)
void build_pairs(const int* __restrict__ nbr, int* __restrict__ pp,
                 int* __restrict__ dd, int* __restrict__ ng, int n)
{
    __shared__ int lnbr[WIN * KV];                  // 20.25 KiB
    __shared__ int cnt[26];
    const int w    = blockIdx.x;
    const int tid  = threadIdx.x;
    const int lane = tid & 63, wv = tid >> 6;
    const long base = (long)w * WIN * KV;
    const long lim  = (long)n * KV;
    for (int i = tid; i < WIN * KV; i += 256)
        lnbr[i] = (base + i < lim) ? nbr[base + i] : n;
    __syncthreads();

    for (int s = wv; s < 26; s += 4) {              // non-center k's only
        const int k = (s < 13) ? s : s + 1;
        int run = 0;
        for (int h = 0; h < 3; ++h) {
            const int row = h * 64 + lane;
            const int idx = lnbr[row * KV + k];
            const unsigned long long m = __ballot(idx != n);
            const int pre = __popcll(m & ((1ull << lane) - 1ull));
            const int pos = run + pre;
            if (idx != n && pos < SEGC)
                pp[(long)w * PPW + s * SEGC + pos] = idx | (row << 19);
            run += __popcll(m);
        }
        if (lane == 0) cnt[s] = min(run, SEGC);
    }
    __syncthreads();

    if (tid == 0) {
        int g = 0;
        const int wrow0 = w * WIN;
        for (int cg = 0; cg < 6; ++cg) {            // center k=13, synthetic
            const int l = min(32, n - (wrow0 + cg * 32));
            if (l > 0) dd[(long)w * DSTR + (g++)] =
                           ((cg * 32) << 11) | (l << 5) | 13;
        }
        for (int s = 0; s < 26; ++s) {
            const int k = (s < 13) ? s : s + 1;
            const int c = cnt[s];
            for (int c0 = 0; c0 < c; c0 += 32)
                dd[(long)w * DSTR + (g++)] =
                    ((s * SEGC + c0) << 11) | (min(32, c - c0) << 5) | k;
        }
        ng[w] = g;
    }
}

// =================== main pair-GEMM kernel ===================

__global__ __launch_bounds__(1024, 4)
void spconv_pairs(const unsigned short* __restrict__ fbf16,
                  const unsigned short* __restrict__ wf,
                  const float* __restrict__ bias,
                  const int* __restrict__ pp,
                  const int* __restrict__ dd,
                  const int* __restrict__ ng,
                  float* __restrict__ out,
                  int n, int nwg)
{
    // wlds FIRST: any accidental accs overflow falls off the END of LDS,
    // never into the W fragments. accs has a dump row (WIN) for invalid
    // slots; srw is clamped so accs writes are bounded by construction.
    __shared__ __align__(16) unsigned short wlds[NFRAG * 512];   // 108 KiB
    __shared__ __align__(16) float accs[(WIN + 1) * COUT];       // 48.25 KiB

    const int tid  = threadIdx.x;
    const int lane = tid & 63;
    const int wv   = tid >> 6;
    const int l31  = lane & 31;
    const int e5   = lane >> 5;

    for (int s = tid; s < SLOTS; s += 1024)
        *(u16x8*)&wlds[s * 8] = *(const u16x8*)(wf + (size_t)s * 8);
    for (int s = tid; s < (WIN + 1) * COUT / 4; s += 1024)
        *(f32x4a*)&accs[s * 4] = (f32x4a){0.f, 0.f, 0.f, 0.f};
    __syncthreads();

    // XCD-contiguous block swizzle (bijective for any nwg)
    const int q = nwg >> 3, r8 = nwg & 7;
    const int xcd = blockIdx.x & 7, bidx = blockIdx.x >> 3;
    const int wg  = (xcd < r8 ? xcd * (q + 1) : r8 * (q + 1) + (xcd - r8) * q) + bidx;

    const int  wrow0   = wg * WIN;
    const int  ngroups = ng[wg];
    const int* ddw     = dd + (size_t)wg * DSTR;
    const int* ppw     = pp + (size_t)wg * PPW;

    for (int g = wv; g < ngroups; g += 16) {
        const int d   = ddw[g];
        const int k   = d & 31;
        const int len = (d >> 5) & 63;
        const int off = d >> 11;

        int idx, srw;
        if (k == 13) {                      // center: always-valid, synthetic
            srw = off + l31;
            idx = wrow0 + srw;
        } else {
            const int pr = ppw[off + l31];  // in-bounds even for lanes>=len
            idx = pr & 0x7FFFF;
            srw = (pr >> 19) & 255;
        }
        const bool v = (l31 < len);
        if (!v) srw = WIN;                  // dump row
        srw = min(srw, WIN);                // paranoia clamp (bounds accs)

        bf16x8 a0 = {}, a1 = {};
        if (v) {                            // exec-masked gather (R7 pattern)
            const unsigned short* f = fbf16 + (size_t)idx * CIN + e5 * 8;
            a0 = *(const bf16x8*)(f);       // ci  8*e5 + 0..7
            a1 = *(const bf16x8*)(f + 16);  // ci 16+8*e5 + 0..7
        }

        const int fb = (k << 2) * 512 + lane * 8;
        const bf16x8 b00 = *(const bf16x8*)&wlds[fb];
        const bf16x8 b01 = *(const bf16x8*)&wlds[fb + 512];
        const bf16x8 b10 = *(const bf16x8*)&wlds[fb + 1024];
        const bf16x8 b11 = *(const bf16x8*)&wlds[fb + 1536];

        f32x16 t0 = {}, t1 = {};
        t0 = __builtin_amdgcn_mfma_f32_32x32x16_bf16(a0, b00, t0, 0, 0, 0);
        t1 = __builtin_amdgcn_mfma_f32_32x32x16_bf16(a0, b01, t1, 0, 0, 0);
        t0 = __builtin_amdgcn_mfma_f32_32x32x16_bf16(a1, b10, t0, 0, 0, 0);
        t1 = __builtin_amdgcn_mfma_f32_32x32x16_bf16(a1, b11, t1, 0, 0, 0);

        // scatter D rows -> window rows. D row = (t&3)+8*(t>>2)+4*e5; slot
        // rr's srw lives in lane rr (l31==rr). Constant-index readlanes +
        // cndmask on e5.
#pragma unroll
        for (int t = 0; t < 16; ++t) {
            const int rr0 = (t & 3) + ((t >> 2) << 3);
            const int tr0 = __builtin_amdgcn_readlane(srw, rr0);
            const int tr1 = __builtin_amdgcn_readlane(srw, rr0 + 4);
            const int tr  = e5 ? tr1 : tr0;
            float* rp = &accs[tr * 64 + l31];
            atomicAdd(rp, t0[t]);
            atomicAdd(rp + 32, t1[t]);
        }
    }

    __syncthreads();

    // epilogue: + bias, coalesced dwordx4 stores (dump row ignored)
#pragma unroll
    for (int j = 0; j < 3; ++j) {
        const int e   = tid + j * 1024;      // vec4 slot (3072 total)
        const int row = e >> 4;
        const int c4  = (e & 15) << 2;
        if (wrow0 + row < n) {
            f32x4a vv = *(const f32x4a*)&accs[row * 64 + c4];
            const f32x4a bv = *(const f32x4a*)(bias + c4);
            vv.x += bv.x; vv.y += bv.y; vv.z += bv.z; vv.w += bv.w;
            *(f32x4a*)(out + (size_t)(wrow0 + row) * COUT + c4) = vv;
        }
    }
}

// =================== fallback kernels (verified R12 / R9) ===================

#define W_PROLOGUE()                                                        \
    do {                                                                    \
        _Pragma("unroll")                                                   \
        for (int i = 0; i < 7; ++i) {                                       \
            const int s = tid + 1024 * i;                                   \
            if (s < SLOTS) {                                                \
                const int frag = s >> 6;                                    \
                const int ln   = s & 63;                                    \
                const int k    = frag >> 2;                                 \
                const int cc   = (frag >> 1) & 1;                           \
                const int h    = frag & 1;                                  \
                const int co   = (ln & 31) + (h << 5);                      \
                const int cib  = (cc << 4) + ((ln >> 5) << 3);              \
                const float* src = weight + k * 2048 + cib * 64 + co;       \
                u16x8 t;                                                    \
                _Pragma("unroll")                                           \
                for (int j = 0; j < 8; ++j)                                 \
                    t[j] = __builtin_bit_cast(unsigned short,               \
                                              (__bf16)src[j * 64]);         \
                *(u16x8*)&wlds[s * 8] = t;                                  \
            }                                                               \
        }                                                                   \
    } while (0)

#define NBR_PRELOAD()                                                       \
    i32x4u nA[6]; i32x2u nB; int nC;                                        \
    do {                                                                    \
        const int* p = nbr + (size_t)min(row, n - 1) * KV;                  \
        _Pragma("unroll")                                                   \
        for (int qq = 0; qq < 6; ++qq) nA[qq] = *(const i32x4u*)(p + 4*qq); \
        nB = *(const i32x2u*)(p + 24);                                      \
        nC = p[26];                                                         \
        if (!rv) {                                                          \
            _Pragma("unroll")                                               \
            for (int qq = 0; qq < 6; ++qq) nA[qq] = i32x4u{n, n, n, n};     \
            nB = i32x2u{n, n};                                              \
            nC = n;                                                         \
        }                                                                   \
    } while (0)

#define EPILOGUE()                                                          \
    do {                                                                    \
        const float bb0 = bias[l31];                                        \
        const float bb1 = bias[l31 + 32];                                   \
        _Pragma("unroll")                                                   \
        for (int t = 0; t < 16; ++t) {                                      \
            const int rr   = (t & 3) + ((t >> 2) << 3) + (e5 << 2);         \
            const int orow = rb + rr;                                       \
            if (orow < n) {                                                 \
                out[(size_t)orow * COUT + l31]      = acc0[t] + bb0;        \
                out[(size_t)orow * COUT + l31 + 32] = acc1[t] + bb1;        \
            }                                                               \
        }                                                                   \
    } while (0)

__global__ __launch_bounds__(1024, 4)
void spconv_mfma_bf16(const unsigned short* __restrict__ fbf16,
                      const float* __restrict__ weight,
                      const float* __restrict__ bias,
                      const int*   __restrict__ nbr,
                      float*       __restrict__ out,
                      int n, int nwg)
{
    __shared__ __align__(16) unsigned short wlds[NFRAG * 512];
    const int tid  = threadIdx.x;
    const int lane = tid & 63;
    const int wv   = tid >> 6;
    const int l31  = lane & 31;
    const int e5   = lane >> 5;
    W_PROLOGUE();
    __syncthreads();
    const int q    = nwg >> 3, r = nwg & 7;
    const int xcd  = blockIdx.x & 7, bidx = blockIdx.x >> 3;
    const int wg   = (xcd < r ? xcd * (q + 1) : r * (q + 1) + (xcd - r) * q) + bidx;
    const int rb = wg * RPB + wv * RPW;
    if (rb >= n) return;
    i32x4 rsrc;
    rsrc.x = (int)(unsigned)(uintptr_t)fbf16;
    rsrc.y = (int)((uintptr_t)fbf16 >> 32);
    rsrc.z = n * (int)(CIN * sizeof(unsigned short));
    rsrc.w = 0x00020000;
    const int  row = rb + l31;
    const bool rv  = row < n;
    NBR_PRELOAD();
    f32x16 acc0 = {}, acc1 = {};
#define GK(kk, P0, P1)                                                     \
    do {                                                                   \
        const int vo_ = (NIDX(nA, nB, nC, (kk)) << 6) + (e5 << 4);         \
        LOADD(P0, P1, vo_, rsrc);                                          \
    } while (0)
    bf16x8 A0a, A0b, A1a, A1b, A2a, A2b, A3a, A3b;
    GK(0, A0a, A0b);
    GK(1, A1a, A1b);
    GK(2, A2a, A2b);
#define KSTEP(CA, CB, PA, PB)                                              \
    do {                                                                   \
        if (k + 3 < KV)       { GK(k + 3, PA, PB); WAIT6(CA, CB); }        \
        else if (k + 3 == KV) { WAIT4(CA, CB); }                           \
        else if (k + 2 == KV) { WAIT2(CA, CB); }                           \
        else                  { WAIT0(CA, CB); }                           \
    } while (0)
#pragma unroll
    for (int k = 0; k < KV; ++k) {
        const int fb = (k << 2) * 512 + lane * 8;
        const bf16x8 b00 = *(const bf16x8*)&wlds[fb];
        const bf16x8 b01 = *(const bf16x8*)&wlds[fb + 512];
        const bf16x8 b10 = *(const bf16x8*)&wlds[fb + 1024];
        const bf16x8 b11 = *(const bf16x8*)&wlds[fb + 1536];
        bf16x8 x0, x1;
        if ((k & 3) == 0)      { KSTEP(A0a, A0b, A3a, A3b); x0 = A0a; x1 = A0b; }
        else if ((k & 3) == 1) { KSTEP(A1a, A1b, A0a, A0b); x0 = A1a; x1 = A1b; }
        else if ((k & 3) == 2) { KSTEP(A2a, A2b, A1a, A1b); x0 = A2a; x1 = A2b; }
        else                   { KSTEP(A3a, A3b, A2a, A2b); x0 = A3a; x1 = A3b; }
        acc0 = __builtin_amdgcn_mfma_f32_32x32x16_bf16(x0, b00, acc0, 0, 0, 0);
        acc1 = __builtin_amdgcn_mfma_f32_32x32x16_bf16(x0, b01, acc1, 0, 0, 0);
        acc0 = __builtin_amdgcn_mfma_f32_32x32x16_bf16(x1, b10, acc0, 0, 0, 0);
        acc1 = __builtin_amdgcn_mfma_f32_32x32x16_bf16(x1, b11, acc1, 0, 0, 0);
    }
#undef KSTEP
#undef GK
    EPILOGUE();
}

__global__ __launch_bounds__(1024, 4)
void spconv_mfma_f32g(const float* __restrict__ feats,
                      const float* __restrict__ weight,
                      const float* __restrict__ bias,
                      const int*   __restrict__ nbr,
                      float*       __restrict__ out,
                      int n, int nwg)
{
    __shared__ __align__(16) unsigned short wlds[NFRAG * 512];
    const int tid  = threadIdx.x;
    const int lane = tid & 63;
    const int wv   = tid >> 6;
    const int l31  = lane & 31;
    const int e5   = lane >> 5;
    W_PROLOGUE();
    __syncthreads();
    const int q    = nwg >> 3, r = nwg & 7;
    const int xcd  = blockIdx.x & 7, bidx = blockIdx.x >> 3;
    const int wg   = (xcd < r ? xcd * (q + 1) : r * (q + 1) + (xcd - r) * q) + bidx;
    const int rb = wg * RPB + wv * RPW;
    if (rb >= n) return;
    i32x4 rsrc;
    rsrc.x = (int)(unsigned)(uintptr_t)feats;
    rsrc.y = (int)((uintptr_t)feats >> 32);
    rsrc.z = n * (int)(CIN * sizeof(float));
    rsrc.w = 0x00020000;
    const int  row = rb + l31;
    const bool rv  = row < n;
    NBR_PRELOAD();
    f32x16 acc0 = {}, acc1 = {};
#define GATHER_K(kk, B0, B1, B2, B3)                                      \
    do {                                                                  \
        const int voff_ = (NIDX(nA, nB, nC, (kk)) << 7) + (e5 << 5);      \
        LOADQ(B0, B1, B2, B3, voff_, rsrc);                               \
    } while (0)
    f32x4a pa0, pa1, pa2, pa3, pb0, pb1, pb2, pb3;
    GATHER_K(0, pa0, pa1, pa2, pa3);
#pragma unroll
    for (int k = 0; k < KV; ++k) {
        const int fb = (k << 2) * 512 + lane * 8;
        const bf16x8 b00 = *(const bf16x8*)&wlds[fb];
        const bf16x8 b01 = *(const bf16x8*)&wlds[fb + 512];
        const bf16x8 b10 = *(const bf16x8*)&wlds[fb + 1024];
        const bf16x8 b11 = *(const bf16x8*)&wlds[fb + 1536];
        bf16x8 x0, x1;
        if ((k & 1) == 0) {
            if (k + 1 < KV) { GATHER_K(k + 1, pb0, pb1, pb2, pb3); WAITV4(pa0, pa1, pa2, pa3); }
            else            { WAITV0(pa0, pa1, pa2, pa3); }
            x0 = cvt8(pa0, pa1); x1 = cvt8(pa2, pa3);
        } else {
            if (k + 1 < KV) { GATHER_K(k + 1, pa0, pa1, pa2, pa3); WAITV4(pb0, pb1, pb2, pb3); }
            else            { WAITV0(pb0, pb1, pb2, pb3); }
            x0 = cvt8(pb0, pb1); x1 = cvt8(pb2, pb3);
        }
        acc0 = __builtin_amdgcn_mfma_f32_32x32x16_bf16(x0, b00, acc0, 0, 0, 0);
        acc1 = __builtin_amdgcn_mfma_f32_32x32x16_bf16(x0, b01, acc1, 0, 0, 0);
        acc0 = __builtin_amdgcn_mfma_f32_32x32x16_bf16(x1, b10, acc0, 0, 0, 0);
        acc1 = __builtin_amdgcn_mfma_f32_32x32x16_bf16(x1, b11, acc1, 0, 0, 0);
    }
#undef GATHER_K
    EPILOGUE();
}

// =================== launcher ===================

extern "C" void kernel_launch(void* const* d_in, const int* in_sizes, int n_in,
                              void* d_out, int out_size, void* d_ws, size_t ws_size,
                              hipStream_t stream)
{
    const float* feats  = (const float*)d_in[0];   // (N, 32) f32
    const float* weight = (const float*)d_in[1];   // (27, 32, 64) f32
    const float* bias   = (const float*)d_in[2];   // (64,) f32
    const int*   nbr    = (const int*)  d_in[3];   // (N, 27) i32, sentinel = N

    float* out = (float*)d_out;                    // (N, 64) f32

    const int n    = in_sizes[0] / CIN;
    const int nwin = (n + WIN - 1) / WIN;

    const size_t fbB = ((size_t)n * CIN * 2 + 255) & ~(size_t)255;
    const size_t wfB = ((size_t)SLOTS * 16 + 255) & ~(size_t)255;
    const size_t ppB = ((size_t)nwin * PPW * 4 + 255) & ~(size_t)255;
    const size_t ddB = ((size_t)nwin * DSTR * 4 + 255) & ~(size_t)255;
    const size_t ngB = ((size_t)nwin * 4 + 255) & ~(size_t)255;
    const size_t need_new  = fbB + wfB + ppB + ddB + ngB;
    const size_t need_bf16 = (size_t)n * CIN * 2;

    if (ws_size >= need_new && n < (1 << 19)) {
        char* base = (char*)d_ws;
        unsigned short* fb = (unsigned short*)base;
        unsigned short* wf = (unsigned short*)(base + fbB);
        int* pp = (int*)(base + fbB + wfB);
        int* dd = (int*)(base + fbB + wfB + ppB);
        int* ng = (int*)(base + fbB + wfB + ppB + ddB);

        feats_to_bf16<<<dim3(2048), dim3(256), 0, stream>>>(feats, fb, n * 4);
        build_wfrag<<<dim3((SLOTS + 255) / 256), dim3(256), 0, stream>>>(weight, wf);
        build_pairs<<<dim3(nwin), dim3(256), 0, stream>>>(nbr, pp, dd, ng, n);
        spconv_pairs<<<dim3(nwin), dim3(1024), 0, stream>>>(
            fb, wf, bias, pp, dd, ng, out, n, nwin);
    } else if (ws_size >= need_bf16) {
        unsigned short* fb = (unsigned short*)d_ws;
        const int nwg = (n + RPB - 1) / RPB;
        feats_to_bf16<<<dim3(2048), dim3(256), 0, stream>>>(feats, fb, n * 4);
        spconv_mfma_bf16<<<dim3(nwg), dim3(1024), 0, stream>>>(
            fb, weight, bias, nbr, out, n, nwg);
    } else {
        const int nwg = (n + RPB - 1) / RPB;
        spconv_mfma_f32g<<<dim3(nwg), dim3(1024), 0, stream>>>(
            feats, weight, bias, nbr, out, n, nwg);
    }
}

// Round 17
// 287.463 us; speedup vs baseline: 2.8641x; 2.8641x over previous
//
#include <hip/hip_runtime.h>

// Sparse submanifold 3D conv via dense bf16 MFMA (32x32x16). Round 17:
// The occupancy experiment, SPILL-FREE. R16 NaN'd: ~74 live VGPR under the
// 64 cap -> allocator spilled regs with in-flight asm buffer_loads (spill
// copy reads a pending-load reg = garbage). This round fits ~58 VGPR:
//  - nbr 14-int register window REPLACED by a 2-reg even/odd idx pipeline,
//    loaded via SRSRC buffer_load_dword inside the counted-vmcnt FIFO:
//    body j: WI2 (retire idx j+1) -> issue idx j+2 -> issue A j+1 ->
//    WA3/WA2 (retire A j) -> 4 MFMAs. All loads are asm; FIFO is exact.
//  - bias preloaded and vmcnt(0)-drained BEFORE the loop so no compiler
//    load can pollute the FIFO counting.
//  - rows >= n never early-return (restage barriers); their nbr reads are
//    SRSRC-OOB -> idx 0 -> harmless row-0 gathers, never stored.
//  - Kept from R12/R16: bf16 feature pre-pass, OOB feature gathers
//    (sentinel n -> zeros), XCD swizzle, fragment-ordered half-k W->LDS
//    staging (56 KiB -> 2 blocks/CU), static indexing everywhere.
// Readout: faster -> 16-wave latency was the limiter. Neutral -> ~75
// cyc/gather-instr TA wall = dense roofline. Fail -> revert R12.
// Fallback (ws too small): R9 f32-gather dense kernel (verified).

typedef short          bf16x8 __attribute__((ext_vector_type(8)));
typedef unsigned short u16x8  __attribute__((ext_vector_type(8)));
typedef float          f32x16 __attribute__((ext_vector_type(16)));
typedef float          f32x4a __attribute__((ext_vector_type(4)));
typedef int            i32x4  __attribute__((ext_vector_type(4)));
typedef int            i32x4u __attribute__((ext_vector_type(4), aligned(4)));
typedef int            i32x2u __attribute__((ext_vector_type(2), aligned(4)));

constexpr int CIN   = 32;
constexpr int COUT  = 64;
constexpr int KV    = 27;
constexpr int KVH1  = 14, KVH2 = 13;   // k's per LDS-resident half
constexpr int WAVES = 16;
constexpr int RPW   = 32;              // rows per wave (one 32x32 tile)
constexpr int RPB   = WAVES * RPW;     // 512 rows per block
constexpr int NFRAG = KV * 4;          // fallback: all fragments
constexpr int SLOTS = NFRAG * 64;

// ---- asm helpers ----
// 2 x buffer_load_dwordx4: one lane's 32B (16 bf16) share of a feature row.
#define LOADD(g0, g1, voff, rs)                                           \
    asm volatile("buffer_load_dwordx4 %0, %2, %3, 0 offen offset:0\n\t"   \
                 "buffer_load_dwordx4 %1, %2, %3, 0 offen offset:32"      \
                 : "=&v"(g0), "=&v"(g1)                                   \
                 : "v"(voff), "s"(rs))
#define LOADP(p, voff, rs)                                                \
    asm volatile("buffer_load_dword %0, %1, %2, 0 offen"                  \
                 : "=&v"(p) : "v"(voff), "s"(rs))
// counted waits, data-tied (no hoisting of consumers above them)
#define WI2(i)      asm volatile("s_waitcnt vmcnt(2)" : "+v"(i))
#define WI1(i)      asm volatile("s_waitcnt vmcnt(1)" : "+v"(i))
#define WA3(a, b)   asm volatile("s_waitcnt vmcnt(3)" : "+v"(a), "+v"(b))
#define WA2(a, b)   asm volatile("s_waitcnt vmcnt(2)" : "+v"(a), "+v"(b))
#define WA0(a, b)   asm volatile("s_waitcnt vmcnt(0)" : "+v"(a), "+v"(b))
#define DRAIN2(a, b) asm volatile("s_waitcnt vmcnt(0)" : "+v"(a), "+v"(b))

// f32 variants (fallback kernel)
#define LOADQ(g0, g1, g2, g3, voff, rs)                                   \
    asm volatile("buffer_load_dwordx4 %0, %4, %5, 0 offen offset:0\n\t"   \
                 "buffer_load_dwordx4 %1, %4, %5, 0 offen offset:16\n\t"  \
                 "buffer_load_dwordx4 %2, %4, %5, 0 offen offset:64\n\t"  \
                 "buffer_load_dwordx4 %3, %4, %5, 0 offen offset:80"      \
                 : "=&v"(g0), "=&v"(g1), "=&v"(g2), "=&v"(g3)             \
                 : "v"(voff), "s"(rs))
#define WAITV4(a, b, c, d) \
    asm volatile("s_waitcnt vmcnt(4)" : "+v"(a), "+v"(b), "+v"(c), "+v"(d))
#define WAITV0(a, b, c, d) \
    asm volatile("s_waitcnt vmcnt(0)" : "+v"(a), "+v"(b), "+v"(c), "+v"(d))

__device__ inline bf16x8 cvt8(f32x4a lo, f32x4a hi) {
    bf16x8 r;
#pragma unroll
    for (int j = 0; j < 4; ++j) {
        r[j]     = __builtin_bit_cast(short, (__bf16)lo[j]);
        r[4 + j] = __builtin_bit_cast(short, (__bf16)hi[j]);
    }
    return r;
}

#define NIDX(A, B, C, k) ((k) < 24 ? (A)[(k) >> 2][(k) & 3] \
                                   : ((k) < 26 ? (B)[(k) - 24] : (C)))

// ---- pre-pass: features f32 -> bf16 into workspace ----
__global__ __launch_bounds__(256)
void feats_to_bf16(const float* __restrict__ in,
                   unsigned short* __restrict__ outp, int ngroups)
{
    int i = blockIdx.x * 256 + threadIdx.x;
    const int stride = gridDim.x * 256;
    for (; i < ngroups; i += stride) {
        const f32x4a a = *(const f32x4a*)(in + (size_t)i * 8);
        const f32x4a b = *(const f32x4a*)(in + (size_t)i * 8 + 4);
        u16x8 t;
#pragma unroll
        for (int j = 0; j < 4; ++j) {
            t[j]     = __builtin_bit_cast(unsigned short, (__bf16)a[j]);
            t[4 + j] = __builtin_bit_cast(unsigned short, (__bf16)b[j]);
        }
        *(u16x8*)(outp + (size_t)i * 8) = t;
    }
}

// stage k's [k0, k0+nk) of W into wlds, fragment-ordered bf16 (R11-verified)
#define STAGE_HALF(k0, nk)                                                  \
    do {                                                                    \
        _Pragma("unroll")                                                   \
        for (int i_ = 0; i_ < 4; ++i_) {                                    \
            const int s_ = tid + 1024 * i_;                                 \
            if (s_ < (nk) * 256) {                                          \
                const int fl_ = s_ >> 6;                                    \
                const int ln_ = s_ & 63;                                    \
                const int k_  = (k0) + (fl_ >> 2);                          \
                const int cc_ = (fl_ >> 1) & 1;                             \
                const int h_  = fl_ & 1;                                    \
                const int co_ = (ln_ & 31) + (h_ << 5);                     \
                const int ci_ = (cc_ << 4) + ((ln_ >> 5) << 3);             \
                const float* src_ = weight + k_ * 2048 + ci_ * 64 + co_;    \
                u16x8 t_;                                                   \
                _Pragma("unroll")                                           \
                for (int j_ = 0; j_ < 8; ++j_)                              \
                    t_[j_] = __builtin_bit_cast(unsigned short,             \
                                                (__bf16)src_[j_ * 64]);     \
                *(u16x8*)&wlds[s_ * 8] = t_;                                \
            }                                                               \
        }                                                                   \
    } while (0)

// one k-half. All VMEM in the loop is OUR asm (exact FIFO):
// prologue: P0, P1, WI1 (P0 done), D0.
// body j:  [entering out: P_{j+1}, D_j(2)]
//   WI2 (P_{j+1} done) -> LOADP P_{j+2} -> LOADD D_{j+1} -> WA3/WA2 (D_j
//   done) -> 4 MFMAs.  Last body: WA0.
#define HALF_PASS(K0, NK)                                                   \
    do {                                                                    \
        int iE, iO;                                                         \
        bf16x8 ea, eb, oa, ob;                                              \
        LOADP(iE, nb + (K0) * 4, nrsrc);                                    \
        LOADP(iO, nb + ((K0) + 1) * 4, nrsrc);                              \
        WI1(iE);                                                            \
        { const int vo = (iE << 6) + (e5 << 4); LOADD(ea, eb, vo, frsrc); } \
        _Pragma("unroll")                                                   \
        for (int j = 0; j < (NK); ++j) {                                    \
            const int fb = (j << 2) * 512 + lane * 8;                       \
            const bf16x8 b00 = *(const bf16x8*)&wlds[fb];                   \
            const bf16x8 b01 = *(const bf16x8*)&wlds[fb + 512];             \
            const bf16x8 b10 = *(const bf16x8*)&wlds[fb + 1024];            \
            const bf16x8 b11 = *(const bf16x8*)&wlds[fb + 1536];            \
            bf16x8 x0, x1;                                                  \
            if ((j & 1) == 0) {                                             \
                if (j + 1 < (NK)) {                                         \
                    WI2(iO);                                                \
                    if (j + 2 < (NK)) LOADP(iE, nb + ((K0) + j + 2) * 4, nrsrc); \
                    { const int vo = (iO << 6) + (e5 << 4);                 \
                      LOADD(oa, ob, vo, frsrc); }                           \
                    if (j + 2 < (NK)) { WA3(ea, eb); } else { WA2(ea, eb); }\
                } else { WA0(ea, eb); }                                     \
                x0 = ea; x1 = eb;                                           \
            } else {                                                        \
                if (j + 1 < (NK)) {                                         \
                    WI2(iE);                                                \
                    if (j + 2 < (NK)) LOADP(iO, nb + ((K0) + j + 2) * 4, nrsrc); \
                    { const int vo = (iE << 6) + (e5 << 4);                 \
                      LOADD(ea, eb, vo, frsrc); }                           \
                    if (j + 2 < (NK)) { WA3(oa, ob); } else { WA2(oa, ob); }\
                } else { WA0(oa, ob); }                                     \
                x0 = oa; x1 = ob;                                           \
            }                                                               \
            acc0 = __builtin_amdgcn_mfma_f32_32x32x16_bf16(x0, b00, acc0, 0, 0, 0); \
            acc1 = __builtin_amdgcn_mfma_f32_32x32x16_bf16(x0, b01, acc1, 0, 0, 0); \
            acc0 = __builtin_amdgcn_mfma_f32_32x32x16_bf16(x1, b10, acc0, 0, 0, 0); \
            acc1 = __builtin_amdgcn_mfma_f32_32x32x16_bf16(x1, b11, acc1, 0, 0, 0); \
        }                                                                   \
    } while (0)

// ---- main kernel: 56 KiB LDS, 2-reg idx pipeline, target 2 blocks/CU ----
__global__ __launch_bounds__(1024, 8)
void spconv_half(const unsigned short* __restrict__ fbf16,
                 const float* __restrict__ weight,
                 const float* __restrict__ bias,
                 const int*   __restrict__ nbr,
                 float*       __restrict__ out,
                 int n, int nwg)
{
    __shared__ __align__(16) unsigned short wlds[KVH1 * 4 * 512];  // 56 KiB

    const int tid  = threadIdx.x;
    const int lane = tid & 63;
    const int wv   = tid >> 6;
    const int l31  = lane & 31;
    const int e5   = lane >> 5;

    // bias preloaded AND drained so it never pollutes the loop's vmcnt FIFO
    float bb0 = bias[l31];
    float bb1 = bias[l31 + 32];
    DRAIN2(bb0, bb1);

    STAGE_HALF(0, KVH1);
    __syncthreads();                     // drains vmcnt/lgkmcnt fully

    // XCD-contiguous block swizzle (bijective for any nwg)
    const int q    = nwg >> 3, r = nwg & 7;
    const int xcd  = blockIdx.x & 7, bidx = blockIdx.x >> 3;
    const int wg   = (xcd < r ? xcd * (q + 1) : r * (q + 1) + (xcd - r) * q) + bidx;

    const int rb = wg * RPB + wv * RPW;  // NO early return (restage barriers)

    // SRSRC over bf16 features: 64 B/row; sentinel row n -> OOB -> zeros
    i32x4 frsrc;
    frsrc.x = (int)(unsigned)(uintptr_t)fbf16;
    frsrc.y = (int)((uintptr_t)fbf16 >> 32);
    frsrc.z = n * (int)(CIN * sizeof(unsigned short));
    frsrc.w = 0x00020000;
    // SRSRC over nbr: 108 B/row; rows >= n -> OOB -> idx 0 (harmless)
    i32x4 nrsrc;
    nrsrc.x = (int)(unsigned)(uintptr_t)nbr;
    nrsrc.y = (int)((uintptr_t)nbr >> 32);
    nrsrc.z = n * (int)(KV * sizeof(int));
    nrsrc.w = 0x00020000;

    const int row = rb + l31;
    const int nb  = row * (KV * 4);      // byte offset of this row's nbr[0]

    f32x16 acc0 = {}, acc1 = {};

    HALF_PASS(0, KVH1);
    __syncthreads();
    STAGE_HALF(KVH1, KVH2);
    __syncthreads();
    HALF_PASS(KVH1, KVH2);

    // epilogue: C/D layout col=lane&31, row=(t&3)+8*(t>>2)+4*e5
#pragma unroll
    for (int t = 0; t < 16; ++t) {
        const int rr   = (t & 3) + ((t >> 2) << 3) + (e5 << 2);
        const int orow = rb + rr;
        if (orow < n) {
            out[(size_t)orow * COUT + l31]      = acc0[t] + bb0;
            out[(size_t)orow * COUT + l31 + 32] = acc1[t] + bb1;
        }
    }
}

// ---- fallback kernel (verified R9): f32 gathers, full 108 KiB LDS ----
__global__ __launch_bounds__(1024, 4)
void spconv_mfma_f32g(const float* __restrict__ feats,
                      const float* __restrict__ weight,
                      const float* __restrict__ bias,
                      const int*   __restrict__ nbr,
                      float*       __restrict__ out,
                      int n, int nwg)
{
    __shared__ __align__(16) unsigned short wlds[NFRAG * 512];

    const int tid  = threadIdx.x;
    const int lane = tid & 63;
    const int wv   = tid >> 6;
    const int l31  = lane & 31;
    const int e5   = lane >> 5;

#pragma unroll
    for (int i = 0; i < 7; ++i) {
        const int s = tid + 1024 * i;
        if (s < SLOTS) {
            const int frag = s >> 6;
            const int ln   = s & 63;
            const int k    = frag >> 2;
            const int cc   = (frag >> 1) & 1;
            const int hh   = frag & 1;
            const int co   = (ln & 31) + (hh << 5);
            const int cib  = (cc << 4) + ((ln >> 5) << 3);
            const float* src = weight + k * 2048 + cib * 64 + co;
            u16x8 t;
#pragma unroll
            for (int j = 0; j < 8; ++j)
                t[j] = __builtin_bit_cast(unsigned short, (__bf16)src[j * 64]);
            *(u16x8*)&wlds[s * 8] = t;
        }
    }
    __syncthreads();

    const int q    = nwg >> 3, r = nwg & 7;
    const int xcd  = blockIdx.x & 7, bidx = blockIdx.x >> 3;
    const int wg   = (xcd < r ? xcd * (q + 1) : r * (q + 1) + (xcd - r) * q) + bidx;

    const int rb = wg * RPB + wv * RPW;
    if (rb >= n) return;

    i32x4 rsrc;
    rsrc.x = (int)(unsigned)(uintptr_t)feats;
    rsrc.y = (int)((uintptr_t)feats >> 32);
    rsrc.z = n * (int)(CIN * sizeof(float));
    rsrc.w = 0x00020000;

    const int  row = rb + l31;
    const bool rv  = row < n;
    const int* pp  = nbr + (size_t)min(row, n - 1) * KV;
    i32x4u nA[6]; i32x2u nB; int nC;
#pragma unroll
    for (int qq = 0; qq < 6; ++qq) nA[qq] = *(const i32x4u*)(pp + 4 * qq);
    nB = *(const i32x2u*)(pp + 24);
    nC = pp[26];
    if (!rv) {
#pragma unroll
        for (int qq = 0; qq < 6; ++qq) nA[qq] = i32x4u{n, n, n, n};
        nB = i32x2u{n, n};
        nC = n;
    }

    f32x16 acc0 = {}, acc1 = {};

#define GATHER_K(kk, B0, B1, B2, B3)                                      \
    do {                                                                  \
        const int voff_ = (NIDX(nA, nB, nC, (kk)) << 7) + (e5 << 5);      \
        LOADQ(B0, B1, B2, B3, voff_, rsrc);                               \
    } while (0)

    f32x4a pa0, pa1, pa2, pa3, pb0, pb1, pb2, pb3;
    GATHER_K(0, pa0, pa1, pa2, pa3);
#pragma unroll
    for (int k = 0; k < KV; ++k) {
        const int fb = (k << 2) * 512 + lane * 8;
        const bf16x8 b00 = *(const bf16x8*)&wlds[fb];
        const bf16x8 b01 = *(const bf16x8*)&wlds[fb + 512];
        const bf16x8 b10 = *(const bf16x8*)&wlds[fb + 1024];
        const bf16x8 b11 = *(const bf16x8*)&wlds[fb + 1536];

        bf16x8 x0, x1;
        if ((k & 1) == 0) {
            if (k + 1 < KV) { GATHER_K(k + 1, pb0, pb1, pb2, pb3); WAITV4(pa0, pa1, pa2, pa3); }
            else            { WAITV0(pa0, pa1, pa2, pa3); }
            x0 = cvt8(pa0, pa1); x1 = cvt8(pa2, pa3);
        } else {
            if (k + 1 < KV) { GATHER_K(k + 1, pa0, pa1, pa2, pa3); WAITV4(pb0, pb1, pb2, pb3); }
            else            { WAITV0(pb0, pb1, pb2, pb3); }
            x0 = cvt8(pb0, pb1); x1 = cvt8(pb2, pb3);
        }

        acc0 = __builtin_amdgcn_mfma_f32_32x32x16_bf16(x0, b00, acc0, 0, 0, 0);
        acc1 = __builtin_amdgcn_mfma_f32_32x32x16_bf16(x0, b01, acc1, 0, 0, 0);
        acc0 = __builtin_amdgcn_mfma_f32_32x32x16_bf16(x1, b10, acc0, 0, 0, 0);
        acc1 = __builtin_amdgcn_mfma_f32_32x32x16_bf16(x1, b11, acc1, 0, 0, 0);
    }
#undef GATHER_K

    const float bb0 = bias[l31];
    const float bb1 = bias[l31 + 32];
#pragma unroll
    for (int t = 0; t < 16; ++t) {
        const int rr   = (t & 3) + ((t >> 2) << 3) + (e5 << 2);
        const int orow = rb + rr;
        if (orow < n) {
            out[(size_t)orow * COUT + l31]      = acc0[t] + bb0;
            out[(size_t)orow * COUT + l31 + 32] = acc1[t] + bb1;
        }
    }
}

// =================== launcher ===================

extern "C" void kernel_launch(void* const* d_in, const int* in_sizes, int n_in,
                              void* d_out, int out_size, void* d_ws, size_t ws_size,
                              hipStream_t stream)
{
    const float* feats  = (const float*)d_in[0];   // (N, 32) f32
    const float* weight = (const float*)d_in[1];   // (27, 32, 64) f32
    const float* bias   = (const float*)d_in[2];   // (64,) f32
    const int*   nbr    = (const int*)  d_in[3];   // (N, 27) i32, sentinel = N

    float* out = (float*)d_out;                    // (N, 64) f32

    const int n   = in_sizes[0] / CIN;
    const int nwg = (n + RPB - 1) / RPB;

    const size_t need = (size_t)n * CIN * sizeof(unsigned short);
    if (ws_size >= need) {
        unsigned short* fb = (unsigned short*)d_ws;
        feats_to_bf16<<<dim3(2048), dim3(256), 0, stream>>>(feats, fb, n * 4);
        spconv_half<<<dim3(nwg), dim3(1024), 0, stream>>>(
            fb, weight, bias, nbr, out, n, nwg);
    } else {
        spconv_mfma_f32g<<<dim3(nwg), dim3(1024), 0, stream>>>(
            feats, weight, bias, nbr, out, n, nwg);
    }
}

// Round 18
// 126.763 us; speedup vs baseline: 6.4949x; 2.2677x over previous
//
#include <hip/hip_runtime.h>

// Sparse submanifold 3D conv via dense bf16 MFMA (32x32x16). Round 18:
// Occupancy experiment at the REGISTER-FEASIBLE point. R16/R17 proved
// 8 waves/SIMD (VGPR<=64) always spills (R17: VGPR=32, 426MB scratch
// traffic, 287us). R11's data shows more waves DO cut per-gather-instr
// cost (2x instrs at 72% occ = 110us = 55% of R12's per-instr cost).
// This round targets 6 waves/SIMD (VGPR cap 84, fits our ~70):
//  - 512-thread blocks (8 waves x 32 rows); LDS = ONE-THIRD of k-range
//    (9 k's, 36,864B) staged 3x per block -> 3 blocks/CU by LDS.
//  - __launch_bounds__(512, 6): 24 waves/CU (vs R12's 16), VGPR cap 84.
//  - per-third 9-int nbr window, drained (data-tied vmcnt(0)) before the
//    gather FIFO so compiler loads can't pollute vmcnt counting.
//  - gather instr count IDENTICAL to R12 (no work duplication).
// Readout: faster -> occupancy governs gather throughput; neutral -> the
// ~60cyc/gather-instr L1/TA wall is structural, revert R12 + roofline.
// Guard: WRITE_SIZE >> 100MB or absmax blowup = spill -> revert R12.
// Fallback (ws too small): R9 f32-gather dense kernel (verified).

typedef short          bf16x8 __attribute__((ext_vector_type(8)));
typedef unsigned short u16x8  __attribute__((ext_vector_type(8)));
typedef float          f32x16 __attribute__((ext_vector_type(16)));
typedef float          f32x4a __attribute__((ext_vector_type(4)));
typedef int            i32x4  __attribute__((ext_vector_type(4)));
typedef int            i32x4u __attribute__((ext_vector_type(4), aligned(4)));
typedef int            i32x2u __attribute__((ext_vector_type(2), aligned(4)));

constexpr int CIN   = 32;
constexpr int COUT  = 64;
constexpr int KV    = 27;
constexpr int KT    = 9;               // k's per LDS-resident third
constexpr int RPW   = 32;              // rows per wave
constexpr int WPB   = 8;               // waves per block (512 threads)
constexpr int RPB   = WPB * RPW;       // 256 rows per block
constexpr int TSLOT = KT * 4 * 64;     // 2304 b128 slots per third
// fallback geometry (R9: 1024 threads, 512 rows)
constexpr int NFRAG = KV * 4;
constexpr int SLOTS = NFRAG * 64;
constexpr int RPB_FB = 512;

// ---- asm helpers ----
// 2 x buffer_load_dwordx4: one lane's 32B (16 bf16) share of a feature row.
#define LOADD(g0, g1, voff, rs)                                           \
    asm volatile("buffer_load_dwordx4 %0, %2, %3, 0 offen offset:0\n\t"   \
                 "buffer_load_dwordx4 %1, %2, %3, 0 offen offset:32"      \
                 : "=&v"(g0), "=&v"(g1)                                   \
                 : "v"(voff), "s"(rs))
#define WAIT2(a, b) asm volatile("s_waitcnt vmcnt(2)" : "+v"(a), "+v"(b))
#define WAIT0(a, b) asm volatile("s_waitcnt vmcnt(0)" : "+v"(a), "+v"(b))

// f32 variants (fallback kernel)
#define LOADQ(g0, g1, g2, g3, voff, rs)                                   \
    asm volatile("buffer_load_dwordx4 %0, %4, %5, 0 offen offset:0\n\t"   \
                 "buffer_load_dwordx4 %1, %4, %5, 0 offen offset:16\n\t"  \
                 "buffer_load_dwordx4 %2, %4, %5, 0 offen offset:64\n\t"  \
                 "buffer_load_dwordx4 %3, %4, %5, 0 offen offset:80"      \
                 : "=&v"(g0), "=&v"(g1), "=&v"(g2), "=&v"(g3)             \
                 : "v"(voff), "s"(rs))
#define WAITV4(a, b, c, d) \
    asm volatile("s_waitcnt vmcnt(4)" : "+v"(a), "+v"(b), "+v"(c), "+v"(d))
#define WAITV0(a, b, c, d) \
    asm volatile("s_waitcnt vmcnt(0)" : "+v"(a), "+v"(b), "+v"(c), "+v"(d))

__device__ inline bf16x8 cvt8(f32x4a lo, f32x4a hi) {
    bf16x8 r;
#pragma unroll
    for (int j = 0; j < 4; ++j) {
        r[j]     = __builtin_bit_cast(short, (__bf16)lo[j]);
        r[4 + j] = __builtin_bit_cast(short, (__bf16)hi[j]);
    }
    return r;
}

#define NIDX(A, B, C, k) ((k) < 24 ? (A)[(k) >> 2][(k) & 3] \
                                   : ((k) < 26 ? (B)[(k) - 24] : (C)))

// ---- pre-pass: features f32 -> bf16 into workspace ----
__global__ __launch_bounds__(256)
void feats_to_bf16(const float* __restrict__ in,
                   unsigned short* __restrict__ outp, int ngroups)
{
    int i = blockIdx.x * 256 + threadIdx.x;
    const int stride = gridDim.x * 256;
    for (; i < ngroups; i += stride) {
        const f32x4a a = *(const f32x4a*)(in + (size_t)i * 8);
        const f32x4a b = *(const f32x4a*)(in + (size_t)i * 8 + 4);
        u16x8 t;
#pragma unroll
        for (int j = 0; j < 4; ++j) {
            t[j]     = __builtin_bit_cast(unsigned short, (__bf16)a[j]);
            t[4 + j] = __builtin_bit_cast(unsigned short, (__bf16)b[j]);
        }
        *(u16x8*)(outp + (size_t)i * 8) = t;
    }
}

// stage k's [k0, k0+KT) of W into wlds, fragment-ordered bf16 (512 threads)
#define STAGE_THIRD(k0)                                                     \
    do {                                                                    \
        _Pragma("unroll")                                                   \
        for (int i_ = 0; i_ < 5; ++i_) {                                    \
            const int s_ = tid + 512 * i_;                                  \
            if (s_ < TSLOT) {                                               \
                const int fl_ = s_ >> 6;                                    \
                const int ln_ = s_ & 63;                                    \
                const int k_  = (k0) + (fl_ >> 2);                          \
                const int cc_ = (fl_ >> 1) & 1;                             \
                const int h_  = fl_ & 1;                                    \
                const int co_ = (ln_ & 31) + (h_ << 5);                     \
                const int ci_ = (cc_ << 4) + ((ln_ >> 5) << 3);             \
                const float* src_ = weight + k_ * 2048 + ci_ * 64 + co_;    \
                u16x8 t_;                                                   \
                _Pragma("unroll")                                           \
                for (int j_ = 0; j_ < 8; ++j_)                              \
                    t_[j_] = __builtin_bit_cast(unsigned short,             \
                                                (__bf16)src_[j_ * 64]);     \
                *(u16x8*)&wlds[s_ * 8] = t_;                                \
            }                                                               \
        }                                                                   \
    } while (0)

// 9-slot nbr window accessor (j literal -> folds at unroll)
#define NJ9(j) ((j) < 4 ? m0[(j) & 3] : (j) < 8 ? m1[(j) & 3] : m8)

// one k-third: 9-int window (drained), depth-1 even/odd A-pipeline,
// full 4 MFMAs per k (no work duplication)
#define THIRD_PASS(K0)                                                      \
    do {                                                                    \
        const int* pk = p + (K0);                                           \
        i32x4u m0 = *(const i32x4u*)(pk);                                   \
        i32x4u m1 = *(const i32x4u*)(pk + 4);                               \
        int    m8 = pk[8];                                                  \
        if (!rv) { m0 = i32x4u{n, n, n, n}; m1 = m0; m8 = n; }              \
        /* pin window loads complete: FIFO below is exclusively ours */     \
        asm volatile("s_waitcnt vmcnt(0)" : "+v"(m0), "+v"(m1), "+v"(m8));  \
        bf16x8 ea, eb, oa, ob;                                              \
        { const int vo = (NJ9(0) << 6) + (e5 << 4);                         \
          LOADD(ea, eb, vo, frsrc); }                                       \
        _Pragma("unroll")                                                   \
        for (int j = 0; j < KT; ++j) {                                      \
            const int fb = (j << 2) * 512 + lane * 8;                       \
            const bf16x8 b00 = *(const bf16x8*)&wlds[fb];                   \
            const bf16x8 b01 = *(const bf16x8*)&wlds[fb + 512];             \
            const bf16x8 b10 = *(const bf16x8*)&wlds[fb + 1024];            \
            const bf16x8 b11 = *(const bf16x8*)&wlds[fb + 1536];            \
            bf16x8 x0, x1;                                                  \
            if ((j & 1) == 0) {                                             \
                if (j + 1 < KT) {                                           \
                    const int vo = (NJ9(j + 1) << 6) + (e5 << 4);           \
                    LOADD(oa, ob, vo, frsrc); WAIT2(ea, eb);                \
                } else WAIT0(ea, eb);                                       \
                x0 = ea; x1 = eb;                                           \
            } else {                                                        \
                if (j + 1 < KT) {                                           \
                    const int vo = (NJ9(j + 1) << 6) + (e5 << 4);           \
                    LOADD(ea, eb, vo, frsrc); WAIT2(oa, ob);                \
                } else WAIT0(oa, ob);                                       \
                x0 = oa; x1 = ob;                                           \
            }                                                               \
            acc0 = __builtin_amdgcn_mfma_f32_32x32x16_bf16(x0, b00, acc0, 0, 0, 0); \
            acc1 = __builtin_amdgcn_mfma_f32_32x32x16_bf16(x0, b01, acc1, 0, 0, 0); \
            acc0 = __builtin_amdgcn_mfma_f32_32x32x16_bf16(x1, b10, acc0, 0, 0, 0); \
            acc1 = __builtin_amdgcn_mfma_f32_32x32x16_bf16(x1, b11, acc1, 0, 0, 0); \
        }                                                                   \
    } while (0)

// ---- main kernel: 36.9KB LDS (k-thirds), 512 threads, 6 waves/SIMD ----
__global__ __launch_bounds__(512, 6)
void spconv_third(const unsigned short* __restrict__ fbf16,
                  const float* __restrict__ weight,
                  const float* __restrict__ bias,
                  const int*   __restrict__ nbr,
                  float*       __restrict__ out,
                  int n, int nwg)
{
    __shared__ __align__(16) unsigned short wlds[TSLOT * 8];   // 36,864 B

    const int tid  = threadIdx.x;
    const int lane = tid & 63;
    const int wv   = tid >> 6;
    const int l31  = lane & 31;
    const int e5   = lane >> 5;

    STAGE_THIRD(0);
    __syncthreads();

    // XCD-contiguous block swizzle (bijective for any nwg)
    const int q    = nwg >> 3, r = nwg & 7;
    const int xcd  = blockIdx.x & 7, bidx = blockIdx.x >> 3;
    const int wg   = (xcd < r ? xcd * (q + 1) : r * (q + 1) + (xcd - r) * q) + bidx;

    const int rb = wg * RPB + wv * RPW;   // NO early return (restage barriers)

    // SRSRC over bf16 features: 64 B/row; sentinel row n -> OOB -> zeros
    i32x4 frsrc;
    frsrc.x = (int)(unsigned)(uintptr_t)fbf16;
    frsrc.y = (int)((uintptr_t)fbf16 >> 32);
    frsrc.z = n * (int)(CIN * sizeof(unsigned short));
    frsrc.w = 0x00020000;

    const int  row = rb + l31;
    const bool rv  = row < n;
    const int* p   = nbr + (size_t)min(row, n - 1) * KV;

    f32x16 acc0 = {}, acc1 = {};

    THIRD_PASS(0);
    __syncthreads();
    STAGE_THIRD(KT);
    __syncthreads();
    THIRD_PASS(KT);
    __syncthreads();
    STAGE_THIRD(2 * KT);
    __syncthreads();
    THIRD_PASS(2 * KT);

    // epilogue: C/D layout col=lane&31, row=(t&3)+8*(t>>2)+4*e5
    const float bb0 = bias[l31];
    const float bb1 = bias[l31 + 32];
#pragma unroll
    for (int t = 0; t < 16; ++t) {
        const int rr   = (t & 3) + ((t >> 2) << 3) + (e5 << 2);
        const int orow = rb + rr;
        if (orow < n) {
            out[(size_t)orow * COUT + l31]      = acc0[t] + bb0;
            out[(size_t)orow * COUT + l31 + 32] = acc1[t] + bb1;
        }
    }
}

// ---- fallback kernel (verified R9): f32 gathers, full 108 KiB LDS ----
__global__ __launch_bounds__(1024, 4)
void spconv_mfma_f32g(const float* __restrict__ feats,
                      const float* __restrict__ weight,
                      const float* __restrict__ bias,
                      const int*   __restrict__ nbr,
                      float*       __restrict__ out,
                      int n, int nwg)
{
    __shared__ __align__(16) unsigned short wlds[NFRAG * 512];

    const int tid  = threadIdx.x;
    const int lane = tid & 63;
    const int wv   = tid >> 6;
    const int l31  = lane & 31;
    const int e5   = lane >> 5;

#pragma unroll
    for (int i = 0; i < 7; ++i) {
        const int s = tid + 1024 * i;
        if (s < SLOTS) {
            const int frag = s >> 6;
            const int ln   = s & 63;
            const int k    = frag >> 2;
            const int cc   = (frag >> 1) & 1;
            const int hh   = frag & 1;
            const int co   = (ln & 31) + (hh << 5);
            const int cib  = (cc << 4) + ((ln >> 5) << 3);
            const float* src = weight + k * 2048 + cib * 64 + co;
            u16x8 t;
#pragma unroll
            for (int j = 0; j < 8; ++j)
                t[j] = __builtin_bit_cast(unsigned short, (__bf16)src[j * 64]);
            *(u16x8*)&wlds[s * 8] = t;
        }
    }
    __syncthreads();

    const int q    = nwg >> 3, r = nwg & 7;
    const int xcd  = blockIdx.x & 7, bidx = blockIdx.x >> 3;
    const int wg   = (xcd < r ? xcd * (q + 1) : r * (q + 1) + (xcd - r) * q) + bidx;

    const int rb = wg * RPB_FB + wv * RPW;
    if (rb >= n) return;

    i32x4 rsrc;
    rsrc.x = (int)(unsigned)(uintptr_t)feats;
    rsrc.y = (int)((uintptr_t)feats >> 32);
    rsrc.z = n * (int)(CIN * sizeof(float));
    rsrc.w = 0x00020000;

    const int  row = rb + l31;
    const bool rv  = row < n;
    const int* pp  = nbr + (size_t)min(row, n - 1) * KV;
    i32x4u nA[6]; i32x2u nB; int nC;
#pragma unroll
    for (int qq = 0; qq < 6; ++qq) nA[qq] = *(const i32x4u*)(pp + 4 * qq);
    nB = *(const i32x2u*)(pp + 24);
    nC = pp[26];
    if (!rv) {
#pragma unroll
        for (int qq = 0; qq < 6; ++qq) nA[qq] = i32x4u{n, n, n, n};
        nB = i32x2u{n, n};
        nC = n;
    }

    f32x16 acc0 = {}, acc1 = {};

#define GATHER_K(kk, B0, B1, B2, B3)                                      \
    do {                                                                  \
        const int voff_ = (NIDX(nA, nB, nC, (kk)) << 7) + (e5 << 5);      \
        LOADQ(B0, B1, B2, B3, voff_, rsrc);                               \
    } while (0)

    f32x4a pa0, pa1, pa2, pa3, pb0, pb1, pb2, pb3;
    GATHER_K(0, pa0, pa1, pa2, pa3);
#pragma unroll
    for (int k = 0; k < KV; ++k) {
        const int fb = (k << 2) * 512 + lane * 8;
        const bf16x8 b00 = *(const bf16x8*)&wlds[fb];
        const bf16x8 b01 = *(const bf16x8*)&wlds[fb + 512];
        const bf16x8 b10 = *(const bf16x8*)&wlds[fb + 1024];
        const bf16x8 b11 = *(const bf16x8*)&wlds[fb + 1536];

        bf16x8 x0, x1;
        if ((k & 1) == 0) {
            if (k + 1 < KV) { GATHER_K(k + 1, pb0, pb1, pb2, pb3); WAITV4(pa0, pa1, pa2, pa3); }
            else            { WAITV0(pa0, pa1, pa2, pa3); }
            x0 = cvt8(pa0, pa1); x1 = cvt8(pa2, pa3);
        } else {
            if (k + 1 < KV) { GATHER_K(k + 1, pa0, pa1, pa2, pa3); WAITV4(pb0, pb1, pb2, pb3); }
            else            { WAITV0(pb0, pb1, pb2, pb3); }
            x0 = cvt8(pb0, pb1); x1 = cvt8(pb2, pb3);
        }

        acc0 = __builtin_amdgcn_mfma_f32_32x32x16_bf16(x0, b00, acc0, 0, 0, 0);
        acc1 = __builtin_amdgcn_mfma_f32_32x32x16_bf16(x0, b01, acc1, 0, 0, 0);
        acc0 = __builtin_amdgcn_mfma_f32_32x32x16_bf16(x1, b10, acc0, 0, 0, 0);
        acc1 = __builtin_amdgcn_mfma_f32_32x32x16_bf16(x1, b11, acc1, 0, 0, 0);
    }
#undef GATHER_K

    const float bb0 = bias[l31];
    const float bb1 = bias[l31 + 32];
#pragma unroll
    for (int t = 0; t < 16; ++t) {
        const int rr   = (t & 3) + ((t >> 2) << 3) + (e5 << 2);
        const int orow = rb + rr;
        if (orow < n) {
            out[(size_t)orow * COUT + l31]      = acc0[t] + bb0;
            out[(size_t)orow * COUT + l31 + 32] = acc1[t] + bb1;
        }
    }
}

// =================== launcher ===================

extern "C" void kernel_launch(void* const* d_in, const int* in_sizes, int n_in,
                              void* d_out, int out_size, void* d_ws, size_t ws_size,
                              hipStream_t stream)
{
    const float* feats  = (const float*)d_in[0];   // (N, 32) f32
    const float* weight = (const float*)d_in[1];   // (27, 32, 64) f32
    const float* bias   = (const float*)d_in[2];   // (64,) f32
    const int*   nbr    = (const int*)  d_in[3];   // (N, 27) i32, sentinel = N

    float* out = (float*)d_out;                    // (N, 64) f32

    const int n = in_sizes[0] / CIN;

    const size_t need = (size_t)n * CIN * sizeof(unsigned short);
    if (ws_size >= need) {
        unsigned short* fb = (unsigned short*)d_ws;
        feats_to_bf16<<<dim3(2048), dim3(256), 0, stream>>>(feats, fb, n * 4);
        const int nwg = (n + RPB - 1) / RPB;
        spconv_third<<<dim3(nwg), dim3(512), 0, stream>>>(
            fb, weight, bias, nbr, out, n, nwg);
    } else {
        const int nwg = (n + RPB_FB - 1) / RPB_FB;
        spconv_mfma_f32g<<<dim3(nwg), dim3(1024), 0, stream>>>(
            feats, weight, bias, nbr, out, n, nwg);
    }
}